// Round 1
// baseline (95.588 us; speedup 1.0000x reference)
//
#include <hip/hip_runtime.h>

// Problem constants (from reference): B=32, C=64, H=256, W=256, D=2
constexpr int Bc = 32;
constexpr int Cc = 64;
constexpr int HWc = 256 * 256;      // 65536 spatial elements per channel
constexpr int THREADS = 256;

// One block per (b,c) channel. Argmax over HW elements, then gather grid
// coords at the argmax index with flip (out[...,0]=grid[b,1,idx],
// out[...,1]=grid[b,0,idx]).
__global__ __launch_bounds__(THREADS) void coord_decode_kernel(
    const float* __restrict__ grid,      // [B, 2, HW]
    const float* __restrict__ heat,      // [B, C, HW]
    float* __restrict__ out)             // [B, C, 2]
{
    const int bc = blockIdx.x;           // 0 .. B*C-1
    const int b  = bc >> 6;              // / C (C=64)
    const int tid = threadIdx.x;

    const float4* ch4 = reinterpret_cast<const float4*>(heat + (size_t)bc * HWc);

    float best = -__builtin_huge_valf();
    int   bidx = 0;

    // HW/4 = 16384 float4s, 256 threads -> 64 iterations.
    // Indices increase monotonically per thread, so strict '>' keeps the
    // FIRST (lowest-index) occurrence on ties, matching jnp.argmax.
#pragma unroll 4
    for (int it = 0; it < HWc / 4 / THREADS; ++it) {
        const int i4 = it * THREADS + tid;       // coalesced: lane i -> consecutive 16B
        const float4 v = ch4[i4];
        const int base = i4 * 4;
        if (v.x > best) { best = v.x; bidx = base;     }
        if (v.y > best) { best = v.y; bidx = base + 1; }
        if (v.z > best) { best = v.z; bidx = base + 2; }
        if (v.w > best) { best = v.w; bidx = base + 3; }
    }

    // Wave-level reduce (64 lanes), explicit lowest-index tie-break.
    for (int off = 32; off >= 1; off >>= 1) {
        const float ov = __shfl_down(best, off, 64);
        const int   oi = __shfl_down(bidx, off, 64);
        if (ov > best || (ov == best && oi < bidx)) { best = ov; bidx = oi; }
    }

    // Cross-wave reduce via LDS (4 waves per block).
    __shared__ float svals[THREADS / 64];
    __shared__ int   sidx [THREADS / 64];
    const int wave = tid >> 6;
    if ((tid & 63) == 0) { svals[wave] = best; sidx[wave] = bidx; }
    __syncthreads();

    if (tid == 0) {
#pragma unroll
        for (int w = 1; w < THREADS / 64; ++w) {
            if (svals[w] > best || (svals[w] == best && sidx[w] < bidx)) {
                best = svals[w];
                bidx = sidx[w];
            }
        }
        const float* g = grid + (size_t)b * 2 * HWc;   // [2, HW] for this batch
        // flip=True on last (coord) axis: out[...,0] <- d=1, out[...,1] <- d=0
        out[bc * 2 + 0] = g[HWc + bidx];
        out[bc * 2 + 1] = g[bidx];
    }
}

extern "C" void kernel_launch(void* const* d_in, const int* in_sizes, int n_in,
                              void* d_out, int out_size, void* d_ws, size_t ws_size,
                              hipStream_t stream) {
    const float* grid = (const float*)d_in[0];   // [B, D, H, W] fp32
    const float* heat = (const float*)d_in[1];   // [B, C, H, W] fp32
    float* out = (float*)d_out;                  // [B, C, D] fp32

    coord_decode_kernel<<<Bc * Cc, THREADS, 0, stream>>>(grid, heat, out);
}

// Round 2
// 83.112 us; speedup vs baseline: 1.1501x; 1.1501x over previous
//
#include <hip/hip_runtime.h>

// Problem constants (from reference): B=32, C=64, H=256, W=256, D=2
constexpr int Bc = 32;
constexpr int Cc = 64;
constexpr int HWc = 256 * 256;      // 65536 spatial elements per channel
constexpr int THREADS = 256;

typedef float f32x4 __attribute__((ext_vector_type(4)));

// One block per (b,c) channel. Argmax over HW elements, then gather grid
// coords at the argmax index with flip (out[...,0]=grid[b,1,idx],
// out[...,1]=grid[b,0,idx]).
//
// Streaming argmax: nontemporal loads (no reuse -> don't pollute caches),
// two independent accumulator chains for ILP, explicit 2-deep load batch
// per iteration so VMEM ops issue before the compare chain.
__global__ __launch_bounds__(THREADS) void coord_decode_kernel(
    const float* __restrict__ grid,      // [B, 2, HW]
    const float* __restrict__ heat,      // [B, C, HW]
    float* __restrict__ out)             // [B, C, 2]
{
    const int bc  = blockIdx.x;          // 0 .. B*C-1
    const int b   = bc >> 6;             // / C (C=64)
    const int tid = threadIdx.x;

    const f32x4* ch4 = reinterpret_cast<const f32x4*>(heat + (size_t)bc * HWc);

    float best0 = -__builtin_huge_valf(), best1 = -__builtin_huge_valf();
    int   idx0 = 0, idx1 = 0;

    // 16384 float4s per channel; 512 per iteration (2 per thread, both
    // lane-contiguous segments -> perfectly coalesced 16B/lane).
    constexpr int ITERS = HWc / 4 / (2 * THREADS);   // 32
#pragma unroll 4
    for (int it = 0; it < ITERS; ++it) {
        const int i0 = it * (2 * THREADS) + tid;
        const int i1 = i0 + THREADS;
        const f32x4 v0 = __builtin_nontemporal_load(ch4 + i0);
        const f32x4 v1 = __builtin_nontemporal_load(ch4 + i1);
        const int b0 = i0 * 4, b1 = i1 * 4;
        // Per-stream indices increase monotonically; strict '>' keeps the
        // FIRST (lowest-index) occurrence on ties, matching jnp.argmax.
#pragma unroll
        for (int j = 0; j < 4; ++j)
            if (v0[j] > best0) { best0 = v0[j]; idx0 = b0 + j; }
#pragma unroll
        for (int j = 0; j < 4; ++j)
            if (v1[j] > best1) { best1 = v1[j]; idx1 = b1 + j; }
    }

    // Merge the two streams (explicit lowest-index tie-break).
    float best = best0;
    int   bidx = idx0;
    if (best1 > best || (best1 == best && idx1 < bidx)) { best = best1; bidx = idx1; }

    // Wave-level reduce (64 lanes), explicit lowest-index tie-break.
    for (int off = 32; off >= 1; off >>= 1) {
        const float ov = __shfl_down(best, off, 64);
        const int   oi = __shfl_down(bidx, off, 64);
        if (ov > best || (ov == best && oi < bidx)) { best = ov; bidx = oi; }
    }

    // Cross-wave reduce via LDS (4 waves per block).
    __shared__ float svals[THREADS / 64];
    __shared__ int   sidx [THREADS / 64];
    const int wave = tid >> 6;
    if ((tid & 63) == 0) { svals[wave] = best; sidx[wave] = bidx; }
    __syncthreads();

    if (tid == 0) {
#pragma unroll
        for (int w = 1; w < THREADS / 64; ++w) {
            if (svals[w] > best || (svals[w] == best && sidx[w] < bidx)) {
                best = svals[w];
                bidx = sidx[w];
            }
        }
        const float* g = grid + (size_t)b * 2 * HWc;   // [2, HW] for this batch
        // flip=True on last (coord) axis: out[...,0] <- d=1, out[...,1] <- d=0
        out[bc * 2 + 0] = g[HWc + bidx];
        out[bc * 2 + 1] = g[bidx];
    }
}

extern "C" void kernel_launch(void* const* d_in, const int* in_sizes, int n_in,
                              void* d_out, int out_size, void* d_ws, size_t ws_size,
                              hipStream_t stream) {
    const float* grid = (const float*)d_in[0];   // [B, D, H, W] fp32
    const float* heat = (const float*)d_in[1];   // [B, C, H, W] fp32
    float* out = (float*)d_out;                  // [B, C, D] fp32

    coord_decode_kernel<<<Bc * Cc, THREADS, 0, stream>>>(grid, heat, out);
}